// Round 21
// baseline (91.643 us; speedup 1.0000x reference)
//
#include <hip/hip_runtime.h>
#include <math.h>

#define NEXP 8
#define DIN 128
#define NTOK (16 * 4096)           // 65536
#define BLK_TOK 16                 // tokens per block, shared by 4 waves
#define PITCH 1032                 // LDS floats per token row (1024 + 8 pad)
#define SMEM_BYTES (BLK_TOK * PITCH * 4)   // 66048 B -> 2 blocks/CU

typedef float f32x4 __attribute__((ext_vector_type(4)));
typedef unsigned int u32;
typedef u32 u32x2 __attribute__((ext_vector_type(2)));
typedef u32 u32x4 __attribute__((ext_vector_type(4)));
typedef short short8 __attribute__((ext_vector_type(8)));

__device__ __forceinline__ u32 pk2(float lo, float hi) {
    // two bf16 (round-half-up): lo -> low 16 bits, hi -> high 16 bits
    return ((__float_as_uint(hi) + 0x8000u) & 0xffff0000u) |
           ((__float_as_uint(lo) + 0x8000u) >> 16);
}

// ---- pack w1/w2 into MFMA fragment order (bf16) in d_ws (verified r13-r20) ----
// P1 (8192 u32): GEMM1 A-frags: entry (nb*4+kb)*64+l, reg c: pair
//   (w1[nb][ch][i], w1[nb][ch+1][i]), ch = kb*32 + (l>>4)*8 + 2c, i = l&15.
// P2 (8192 u32): GEMM2 A-frags (w2), u32x4 per lane covering cb pair:
//   P2[((e*4+cp)*64+l)*4 + c2], s=c2>>1, c=c2&1: pair
//   (w2[e][i0][outc], w2[e][i0+1][outc]), i0=(l>>4)*4+2c, outc=(2cp+s)*16+(l&15).
__global__ void pack_weights_kernel(const float* __restrict__ w1,
                                    const float* __restrict__ w2,
                                    u32* __restrict__ P1u,
                                    u32* __restrict__ P2u) {
    int idx = blockIdx.x * 256 + threadIdx.x;       // 0 .. 16383
    if (idx < 8192) {
        int c     = idx & 3;
        int entry = idx >> 2;
        int l     = entry & 63;
        int nbkb  = entry >> 6;            // 0..31
        int nb = nbkb >> 2, kb = nbkb & 3;
        int qq = l >> 4, row = l & 15;
        int ch = kb * 32 + qq * 8 + 2 * c;
        const float* s = w1 + nb * 2048 + ch * 16 + row;
        P1u[idx] = pk2(s[0], s[16]);
    } else {
        int j     = idx - 8192;            // 0 .. 8191
        int c2    = j & 3;
        int entry = j >> 2;                // 0 .. 2047
        int l     = entry & 63;
        int ecp   = entry >> 6;            // 0..31
        int e = ecp >> 2, cp = ecp & 3;
        int s = c2 >> 1, c = c2 & 1;
        int i0 = (l >> 4) * 4 + 2 * c;
        int outc = (2 * cp + s) * 16 + (l & 15);
        const float* src = w2 + e * 2048 + i0 * 128 + outc;
        P2u[j] = pk2(src[0], src[128]);
    }
}

__global__ __launch_bounds__(256, 1) __attribute__((amdgpu_num_vgpr(128)))
void moe_mfma_kernel(
    const float* __restrict__ x,
    const float* __restrict__ rw,
    const unsigned short* __restrict__ P1,   // packed w1 frags
    const u32* __restrict__ P2,              // packed w2 frags (u32x4/lane)
    float* __restrict__ out_agg,
    float* __restrict__ out_exp)
{
    extern __shared__ float lds[];           // [16 tok][PITCH] block-shared tile

    const int tid  = threadIdx.x;
    const int wave = tid >> 6;
    const int lane = tid & 63;
    const int q    = lane >> 4;
    const int n16  = lane & 15;
    const int btok = blockIdx.x * BLK_TOK;

    // ---- B1 frags (all 16 block tokens; every wave loads the same x) ----
    short8 b1[4];
    {
        const float* xb = x + (size_t)(btok + n16) * DIN + q * 8;
#pragma unroll
        for (int kb = 0; kb < 4; ++kb) {
            f32x4 lo = *(const f32x4*)(xb + kb * 32);
            f32x4 hi = *(const f32x4*)(xb + kb * 32 + 4);
            u32x4 u;
            u.x = pk2(lo.x, lo.y); u.y = pk2(lo.z, lo.w);
            u.z = pk2(hi.x, hi.y); u.w = pk2(hi.z, hi.w);
            b1[kb] = __builtin_bit_cast(short8, u);
        }
    }

    const short8* P1f = (const short8*)P1;
    const u32x4*  P2f = (const u32x4*)P2;
    const f32x4 z = {0.f, 0.f, 0.f, 0.f};

    // ---- wave w handles experts 2w, 2w+1 for all 16 tokens ----
#pragma unroll
    for (int h = 0; h < 2; ++h) {
        const int e = 2 * wave + h;

        // GEMM1 (swapped): c1[r] = y[tok=n16][e][i=4q+r] (verified map)
        f32x4 a = z;
#pragma unroll
        for (int kb = 0; kb < 4; ++kb) {
            short8 af = P1f[(e * 4 + kb) * 64 + lane];
            a = __builtin_amdgcn_mfma_f32_16x16x32_bf16(af, b1[kb], a, 0, 0, 0);
        }

        // exact GELU + bf16 pack
        float g0 = a[0], g1 = a[1], g2 = a[2], g3 = a[3];
        g0 = 0.5f * g0 * (1.f + erff(g0 * 0.70710678118654752f));
        g1 = 0.5f * g1 * (1.f + erff(g1 * 0.70710678118654752f));
        g2 = 0.5f * g2 * (1.f + erff(g2 * 0.70710678118654752f));
        g3 = 0.5f * g3 * (1.f + erff(g3 * 0.70710678118654752f));
        const u32 p0 = pk2(g0, g1);
        const u32 p1 = pk2(g2, g3);
        u32x4 au = {p0, p1, p0, p1};                 // hi half: don't-care (x0)
        short8 gfrag = __builtin_bit_cast(short8, au);

        // GEMM2 swapped: o -> C2s[outc=cb*16+4q+r][tok=n16] -> tile token-major
#pragma unroll
        for (int cp = 0; cp < 4; ++cp) {
            u32x4 W = P2f[(e * 4 + cp) * 64 + lane];
            {
                u32x4 wu = {W.x, W.y, 0u, 0u};       // hi rows = zero
                short8 wf = __builtin_bit_cast(short8, wu);
                f32x4 o = __builtin_amdgcn_mfma_f32_16x16x32_bf16(wf, gfrag, z, 0, 0, 0);
                *(f32x4*)(lds + n16 * PITCH + e * DIN + (2 * cp) * 16 + 4 * q) = o;
            }
            {
                u32x4 wu = {W.z, W.w, 0u, 0u};
                short8 wf = __builtin_bit_cast(short8, wu);
                f32x4 o = __builtin_amdgcn_mfma_f32_16x16x32_bf16(wf, gfrag, z, 0, 0, 0);
                *(f32x4*)(lds + n16 * PITCH + e * DIN + (2 * cp + 1) * 16 + 4 * q) = o;
            }
        }
    }

    __syncthreads();

    // ---- drain out_exp: block writes ONE contiguous 64 KB range ----
    // wave w drains tokens 4w..4w+3; per instr: one contiguous 1 KB quarter-row.
    {
        float* oe = out_exp + (size_t)btok * (NEXP * DIN);
#pragma unroll
        for (int k = 0; k < 16; ++k) {
            const int t  = 4 * wave + (k >> 2);
            const int qr = k & 3;
            f32x4 v = *(const f32x4*)(lds + t * PITCH + qr * 256 + lane * 4);
            *(f32x4*)(oe + (size_t)t * (NEXP * DIN) + qr * 256 + lane * 4) = v;
        }
    }

    // ---- agg from tile: acc = sum_e rw[t][e]*exp[t][e][c] (same e-order) ----
    // wave w handles tokens 4w..4w+3; block writes contiguous 8 KB to out_agg.
    {
        float* oa = out_agg + (size_t)btok * DIN;
#pragma unroll
        for (int i = 0; i < 2; ++i) {
            const int t  = 4 * wave + 2 * i + (lane >> 5);
            const int cq = (lane & 31) * 4;
            const float* rp = rw + (size_t)(btok + t) * NEXP;
            f32x4 rA = *(const f32x4*)rp;            // rw[t][0..3]
            f32x4 rB = *(const f32x4*)(rp + 4);      // rw[t][4..7]
            const float* base = lds + t * PITCH + cq;
            f32x4 acc;
            acc  = rA.x * *(const f32x4*)(base + 0 * DIN);
            acc += rA.y * *(const f32x4*)(base + 1 * DIN);
            acc += rA.z * *(const f32x4*)(base + 2 * DIN);
            acc += rA.w * *(const f32x4*)(base + 3 * DIN);
            acc += rB.x * *(const f32x4*)(base + 4 * DIN);
            acc += rB.y * *(const f32x4*)(base + 5 * DIN);
            acc += rB.z * *(const f32x4*)(base + 6 * DIN);
            acc += rB.w * *(const f32x4*)(base + 7 * DIN);
            *(f32x4*)(oa + (size_t)t * DIN + cq) = acc;
        }
    }
}

extern "C" void kernel_launch(void* const* d_in, const int* in_sizes, int n_in,
                              void* d_out, int out_size, void* d_ws, size_t ws_size,
                              hipStream_t stream) {
    const float* x  = (const float*)d_in[0];
    const float* rw = (const float*)d_in[1];
    const float* w1 = (const float*)d_in[2];
    const float* w2 = (const float*)d_in[3];

    float* out_agg = (float*)d_out;                  // [NTOK][128]
    float* out_exp = out_agg + (size_t)NTOK * DIN;   // [NTOK][8][128]
    u32* P1u = (u32*)d_ws;                           // 32 KB w1 frags
    u32* P2u = P1u + 8192;                           // 32 KB w2 frags

    pack_weights_kernel<<<dim3(64), dim3(256), 0, stream>>>(w1, w2, P1u, P2u);

    // opt in to >64 KB dynamic LDS (66048 B)
    (void)hipFuncSetAttribute((const void*)moe_mfma_kernel,
                              hipFuncAttributeMaxDynamicSharedMemorySize,
                              SMEM_BYTES);

    dim3 grid(NTOK / BLK_TOK);   // 4096
    dim3 block(256);
    moe_mfma_kernel<<<grid, block, SMEM_BYTES, stream>>>(
        x, rw, (const unsigned short*)P1u, P2u, out_agg, out_exp);
}

// Round 22
// 78.500 us; speedup vs baseline: 1.1674x; 1.1674x over previous
//
#include <hip/hip_runtime.h>
#include <math.h>

#define NEXP 8
#define DIN 128
#define NTOK (16 * 4096)           // 65536
// wave = 16 tokens, block = 4 waves = 64 tokens, grid = 1024

#define LPITCH 136                 // LDS pitch (floats) for [16 tok][128 outc] tile
#define LDS_PER_WAVE (16 * LPITCH) // 2176 floats = 8704 B
#define SMEM_BYTES (4 * LDS_PER_WAVE * 4)   // 34816 B

typedef float f32x4 __attribute__((ext_vector_type(4)));
typedef unsigned int u32;
typedef u32 u32x2 __attribute__((ext_vector_type(2)));
typedef u32 u32x4 __attribute__((ext_vector_type(4)));
typedef short short8 __attribute__((ext_vector_type(8)));

__device__ __forceinline__ u32 pk2(float lo, float hi) {
    // two bf16 (round-half-up): lo -> low 16 bits, hi -> high 16 bits
    return ((__float_as_uint(hi) + 0x8000u) & 0xffff0000u) |
           ((__float_as_uint(lo) + 0x8000u) >> 16);
}

// ---- pack w1/w2 into MFMA fragment order (bf16) in d_ws (verified r13-r21) ----
// P1 (8192 u32): GEMM1 A-frags: entry (nb*4+kb)*64+l, reg c: pair
//   (w1[nb][ch][i], w1[nb][ch+1][i]), ch = kb*32 + (l>>4)*8 + 2c, i = l&15.
// P2 (8192 u32): GEMM2 A-frags (w2), u32x4 per lane covering cb pair:
//   P2[((e*4+cp)*64+l)*4 + c2], s=c2>>1, c=c2&1: pair
//   (w2[e][i0][outc], w2[e][i0+1][outc]), i0=(l>>4)*4+2c, outc=(2cp+s)*16+(l&15).
__global__ void pack_weights_kernel(const float* __restrict__ w1,
                                    const float* __restrict__ w2,
                                    u32* __restrict__ P1u,
                                    u32* __restrict__ P2u) {
    int idx = blockIdx.x * 256 + threadIdx.x;       // 0 .. 16383
    if (idx < 8192) {
        int c     = idx & 3;
        int entry = idx >> 2;
        int l     = entry & 63;
        int nbkb  = entry >> 6;            // 0..31
        int nb = nbkb >> 2, kb = nbkb & 3;
        int qq = l >> 4, row = l & 15;
        int ch = kb * 32 + qq * 8 + 2 * c;
        const float* s = w1 + nb * 2048 + ch * 16 + row;
        P1u[idx] = pk2(s[0], s[16]);
    } else {
        int j     = idx - 8192;            // 0 .. 8191
        int c2    = j & 3;
        int entry = j >> 2;                // 0 .. 2047
        int l     = entry & 63;
        int ecp   = entry >> 6;            // 0..31
        int e = ecp >> 2, cp = ecp & 3;
        int s = c2 >> 1, c = c2 & 1;
        int i0 = (l >> 4) * 4 + 2 * c;
        int outc = (2 * cp + s) * 16 + (l & 15);
        const float* src = w2 + e * 2048 + i0 * 128 + outc;
        P2u[j] = pk2(src[0], src[128]);
    }
}

__global__ __launch_bounds__(256, 1) __attribute__((amdgpu_num_vgpr(128)))
void moe_mfma_kernel(
    const float* __restrict__ x,
    const float* __restrict__ rw,
    const unsigned short* __restrict__ P1,   // packed w1 frags
    const u32* __restrict__ P2,              // packed w2 frags (u32x4/lane)
    float* __restrict__ out_agg,
    float* __restrict__ out_exp)
{
    extern __shared__ float lds[];

    const int tid  = threadIdx.x;
    const int wave = tid >> 6;
    const int lane = tid & 63;
    const int q    = lane >> 4;
    const int n16  = lane & 15;
    const int wtok = blockIdx.x * 64 + wave * 16;

    float* Lw = lds + wave * LDS_PER_WAVE;   // wave-private [16][LPITCH] tile

    // ---- B1 frags: position (q,j) of kb-block = x[wtok+n16][kb*32+q*8+j] ----
    short8 b1[4];
    {
        const float* xb = x + (size_t)(wtok + n16) * DIN + q * 8;
#pragma unroll
        for (int kb = 0; kb < 4; ++kb) {
            f32x4 lo = *(const f32x4*)(xb + kb * 32);
            f32x4 hi = *(const f32x4*)(xb + kb * 32 + 4);
            u32x4 u;
            u.x = pk2(lo.x, lo.y); u.y = pk2(lo.z, lo.w);
            u.z = pk2(hi.x, hi.y); u.w = pk2(hi.z, hi.w);
            b1[kb] = __builtin_bit_cast(short8, u);
        }
    }

    // ---- GEMM1 (swapped): c1[e][r] = y[tok=n16][e][i=4q+r] (verified) ----
    const short8* P1f = (const short8*)P1;
    f32x4 c1[8];
#pragma unroll
    for (int nb = 0; nb < 8; ++nb) {
        f32x4 a = {0.f, 0.f, 0.f, 0.f};
#pragma unroll
        for (int kb = 0; kb < 4; ++kb) {
            short8 af = P1f[(nb * 4 + kb) * 64 + lane];
            a = __builtin_amdgcn_mfma_f32_16x16x32_bf16(af, b1[kb], a, 0, 0, 0);
        }
        c1[nb] = a;
    }

    // ---- exact GELU + bf16 pack: pa[e] = (gy[4q+0,1], gy[4q+2,3]) for tok n16 ----
    u32x2 pa[8];
#pragma unroll
    for (int e = 0; e < 8; ++e) {
        float g0 = c1[e][0], g1 = c1[e][1], g2 = c1[e][2], g3 = c1[e][3];
        g0 = 0.5f * g0 * (1.f + erff(g0 * 0.70710678118654752f));
        g1 = 0.5f * g1 * (1.f + erff(g1 * 0.70710678118654752f));
        g2 = 0.5f * g2 * (1.f + erff(g2 * 0.70710678118654752f));
        g3 = 0.5f * g3 * (1.f + erff(g3 * 0.70710678118654752f));
        pa[e].x = pk2(g0, g1);
        pa[e].y = pk2(g2, g3);
    }

    // ---- GEMM2 swapped: o = mfma(w2frag, gyfrag) -> C2s[outc=cb*16+4q+r][tok=n16]
    //      MFMA out -> wave-private LDS (token-major) -> contiguous global stores
    const u32x4* P2f = (const u32x4*)P2;
    f32x4 aggs[8];
#pragma unroll
    for (int cb = 0; cb < 8; ++cb) aggs[cb] = (f32x4){0.f, 0.f, 0.f, 0.f};

    const size_t tok = (size_t)(wtok + n16);
    const f32x4 z = {0.f, 0.f, 0.f, 0.f};
    // read-back/store mapping: instr k covers tokens 2k, 2k+1 (2 x 512 B segments)
    const int rtok = (lane >> 5);            // 0/1: which of the 2 tokens
    const int rc   = (lane & 31) * 4;        // 0..124: outc quad
    const float* rwp = rw + tok * NEXP;

#pragma unroll
    for (int e = 0; e < 8; ++e) {
        u32x4 au = {pa[e].x, pa[e].y, pa[e].x, pa[e].y};    // hi: don't-care (x0)
        short8 gfrag = __builtin_bit_cast(short8, au);
        const float rwe = rwp[e];                           // lane-token uniform

#pragma unroll
        for (int cp = 0; cp < 4; ++cp) {
            u32x4 W = P2f[(e * 4 + cp) * 64 + lane];
            // cb = 2cp
            {
                u32x4 wu = {W.x, W.y, 0u, 0u};              // hi rows = zero
                short8 wf = __builtin_bit_cast(short8, wu);
                f32x4 o = __builtin_amdgcn_mfma_f32_16x16x32_bf16(wf, gfrag, z, 0, 0, 0);
                *(f32x4*)(Lw + n16 * LPITCH + (2 * cp) * 16 + 4 * q) = o;
                aggs[2 * cp] += rwe * o;
            }
            // cb = 2cp+1
            {
                u32x4 wu = {W.z, W.w, 0u, 0u};
                short8 wf = __builtin_bit_cast(short8, wu);
                f32x4 o = __builtin_amdgcn_mfma_f32_16x16x32_bf16(wf, gfrag, z, 0, 0, 0);
                *(f32x4*)(Lw + n16 * LPITCH + (2 * cp + 1) * 16 + 4 * q) = o;
                aggs[2 * cp + 1] += rwe * o;
            }
        }

        // drain expert e: 8 instrs, each storing 2 contiguous 512 B token-rows
        float* oe = out_exp + (size_t)wtok * (NEXP * DIN) + e * DIN;
#pragma unroll
        for (int k = 0; k < 8; ++k) {
            const int t2 = 2 * k + rtok;
            f32x4 v = *(const f32x4*)(Lw + t2 * LPITCH + rc);
            *(f32x4*)(oe + (size_t)t2 * (NEXP * DIN) + rc) = v;
        }
    }

    // ---- agg: same LDS transpose -> contiguous out_agg rows ----
#pragma unroll
    for (int cb = 0; cb < 8; ++cb)
        *(f32x4*)(Lw + n16 * LPITCH + cb * 16 + 4 * q) = aggs[cb];

    float* oa = out_agg + (size_t)wtok * DIN;
#pragma unroll
    for (int k = 0; k < 8; ++k) {
        const int t2 = 2 * k + rtok;
        f32x4 v = *(const f32x4*)(Lw + t2 * LPITCH + rc);
        *(f32x4*)(oa + (size_t)t2 * DIN + rc) = v;
    }
}

extern "C" void kernel_launch(void* const* d_in, const int* in_sizes, int n_in,
                              void* d_out, int out_size, void* d_ws, size_t ws_size,
                              hipStream_t stream) {
    const float* x  = (const float*)d_in[0];
    const float* rw = (const float*)d_in[1];
    const float* w1 = (const float*)d_in[2];
    const float* w2 = (const float*)d_in[3];

    float* out_agg = (float*)d_out;                  // [NTOK][128]
    float* out_exp = out_agg + (size_t)NTOK * DIN;   // [NTOK][8][128]
    u32* P1u = (u32*)d_ws;                           // 32 KB w1 frags
    u32* P2u = P1u + 8192;                           // 32 KB w2 frags

    pack_weights_kernel<<<dim3(64), dim3(256), 0, stream>>>(w1, w2, P1u, P2u);

    dim3 grid(NTOK / 64);   // 1024
    dim3 block(256);
    moe_mfma_kernel<<<grid, block, SMEM_BYTES, stream>>>(
        x, rw, (const unsigned short*)P1u, P2u, out_agg, out_exp);
}